// Round 12
// baseline (43630.301 us; speedup 1.0000x reference)
//
#include <hip/hip_runtime.h>
#include <hip/hip_bf16.h>
#include <stdint.h>

#define S_LEN 4096

typedef __attribute__((ext_vector_type(8))) short short8;   // 8 bf16 in 4 VGPRs (MFMA frag)
typedef __attribute__((ext_vector_type(4))) float f32x4;

__device__ inline unsigned short f2bf(float f) {
  unsigned int x = __float_as_uint(f);
  x += 0x7fffu + ((x >> 16) & 1u);           // RNE; inputs finite
  return (unsigned short)(x >> 16);
}

__device__ inline float sigm(float x) { return 1.0f / (1.0f + __expf(-x)); }
__device__ inline float tanhf_(float x) {
  float e = __expf(-2.0f * fabsf(x));        // e in (0,1]: no overflow
  float t = (1.0f - e) / (1.0f + e);
  return copysignf(t, x);
}

__device__ inline void gload_lds16(const void* g, void* l) {
  __builtin_amdgcn_global_load_lds(
      (const __attribute__((address_space(1))) unsigned int*)g,
      (__attribute__((address_space(3))) unsigned int*)l, 16, 0, 0);
}

// ---------------- embedding gather: x0b[row][0:512) = bf16(E[idx[row]]) ----------------
__global__ void embed_kernel(const int* __restrict__ idx, const float* __restrict__ E,
                             unsigned short* __restrict__ x0b) {
  const int row = blockIdx.x;      // 4096
  const int t = threadIdx.x;       // 128
  const int id = idx[row];
  f32x4 v = ((const f32x4*)(E + (size_t)id * 512))[t];
  ushort4 u;
  u.x = f2bf(v[0]); u.y = f2bf(v[1]); u.z = f2bf(v[2]); u.w = f2bf(v[3]);
  ((ushort4*)(x0b + (size_t)row * 512))[t] = u;
}

// ---------------- f32 -> bf16 bulk convert ----------------
__global__ void f32_to_bf16_kernel(const float* __restrict__ src, unsigned short* __restrict__ dst) {
  const size_t i = (size_t)blockIdx.x * blockDim.x + threadIdx.x;
  f32x4 v = ((const f32x4*)src)[i];
  ushort4 u;
  u.x = f2bf(v[0]); u.y = f2bf(v[1]); u.z = f2bf(v[2]); u.w = f2bf(v[3]);
  ((ushort4*)dst)[i] = u;
}

// ---------------- bf16 MFMA GEMM, C[M][N] = A[M][K] @ B[N][K]^T (+bias) ----------------
template <bool BF32>
__global__ __launch_bounds__(256) void gemm_bt(
    const unsigned short* __restrict__ A,   // [M][K] bf16
    const void* __restrict__ Bsrc,          // [N][K] bf16 or f32
    const float* __restrict__ bias,         // [N] or nullptr
    float* __restrict__ C,                  // [M][N] f32
    int M, int N, int K)
{
  __shared__ unsigned short Al[128 * 32];
  __shared__ unsigned short Bl[128 * 32];
  const int tiles_n = N >> 7;
  const int tm = (blockIdx.x / tiles_n) << 7;
  const int tn = (blockIdx.x % tiles_n) << 7;
  const int t = threadIdx.x;
  const int w = t >> 6, l = t & 63;
  const int wr = w >> 1, wc = w & 1;

  f32x4 acc[4][4] = {};

  for (int k0 = 0; k0 < K; k0 += 32) {
    __syncthreads();
    {
      const int rb = w * 32;
      const unsigned short* ga = A + (size_t)(tm + rb + (l >> 2)) * K + k0 + (l & 3) * 8;
      gload_lds16(ga, &Al[rb * 32]);
      gload_lds16(ga + (size_t)16 * K, &Al[(rb + 16) * 32]);
    }
    if constexpr (!BF32) {
      const unsigned short* B = (const unsigned short*)Bsrc;
      const int rb = w * 32;
      const unsigned short* gb = B + (size_t)(tn + rb + (l >> 2)) * K + k0 + (l & 3) * 8;
      gload_lds16(gb, &Bl[rb * 32]);
      gload_lds16(gb + (size_t)16 * K, &Bl[(rb + 16) * 32]);
    } else {
      const float* B = (const float*)Bsrc;
      const int row = t >> 1, half = t & 1;
      const f32x4* src = (const f32x4*)(B + (size_t)(tn + row) * K + k0 + half * 16);
      f32x4 v0 = src[0], v1 = src[1], v2 = src[2], v3 = src[3];
      short8 p0, p1;
      p0[0] = f2bf(v0[0]); p0[1] = f2bf(v0[1]); p0[2] = f2bf(v0[2]); p0[3] = f2bf(v0[3]);
      p0[4] = f2bf(v1[0]); p0[5] = f2bf(v1[1]); p0[6] = f2bf(v1[2]); p0[7] = f2bf(v1[3]);
      p1[0] = f2bf(v2[0]); p1[1] = f2bf(v2[1]); p1[2] = f2bf(v2[2]); p1[3] = f2bf(v2[3]);
      p1[4] = f2bf(v3[0]); p1[5] = f2bf(v3[1]); p1[6] = f2bf(v3[2]); p1[7] = f2bf(v3[3]);
      *(short8*)&Bl[row * 32 + half * 16] = p0;
      *(short8*)&Bl[row * 32 + half * 16 + 8] = p1;
    }
    __syncthreads();

    const int lrow = l & 15;
    const int lkb = (l >> 4) * 8;
    short8 af[4], bfr[4];
    #pragma unroll
    for (int fm = 0; fm < 4; fm++)
      af[fm] = *(const short8*)&Al[(wr * 64 + fm * 16 + lrow) * 32 + lkb];
    #pragma unroll
    for (int fn = 0; fn < 4; fn++)
      bfr[fn] = *(const short8*)&Bl[(wc * 64 + fn * 16 + lrow) * 32 + lkb];
    #pragma unroll
    for (int fm = 0; fm < 4; fm++)
      #pragma unroll
      for (int fn = 0; fn < 4; fn++)
        acc[fm][fn] = __builtin_amdgcn_mfma_f32_16x16x32_bf16(af[fm], bfr[fn], acc[fm][fn], 0, 0, 0);
  }

  const int r0 = tm + wr * 64;
  const int c0 = tn + wc * 64 + (l & 15);
  const int rbase = (l >> 4) * 4;
  #pragma unroll
  for (int fm = 0; fm < 4; fm++) {
    #pragma unroll
    for (int fn = 0; fn < 4; fn++) {
      const int col = c0 + fn * 16;
      const float bv = bias ? bias[col] : 0.0f;
      #pragma unroll
      for (int rg = 0; rg < 4; rg++) {
        const int rr = r0 + fm * 16 + rbase + rg;
        C[(size_t)rr * N + col] = acc[fm][fn][rg] + bv;
      }
    }
  }
}

// ---------------- bidirectional LSTM layer (overlapped weight stream) ------------------
// grid = 64: dir = bid&1, chunk = bid>>1 (32 chunks of 16 h-elements each). 1 WG/CU.
// Lane map (wave w, lane l): gate g=l>>4, elem-sub jl=(l>>3)&1, oct o=l&7.
// Row r = g*512 + chunk*16 + (w*2+jl); oct o covers h[o*64, o*64+64).
// Key change vs r5/r7/r9 (all ~1.4us/step): in every prior variant the 64KB/WG weight
// stream ended up serialized AFTER h-arrival (allocator sinks plain loads to uses;
// r7's per-load vmcnt(0) asm serialized 16 L2 RTs). Here: poll issued FIRST, then 16
// asm global_load_dwordx4 with NO internal waitcnt (in flight during the poison spin),
// pinned above the poll loop by sched_barrier(0) so LLVM cannot sink them. The
// __syncthreads before the dot drains vmcnt(0) -> wv registers guaranteed valid, at
// zero extra cost. Step = visibility + catch (stream hidden underneath) + dot + act.
// Exchange (r2/r5/r7-proven): Hx dwords on 0xFFFFFFFF-poisoned buffer, relaxed AGENT
// atomics (|h|<1 so poison unreachable); 512 pollers x 1 dword; capped spins ->
// terminates under any pathology. hsh[2][8*68] parity-dbuf conflict-free; ONE
// barrier/step; xproj prefetched one step ahead.
__global__ __launch_bounds__(512, 1) void lstm_layer(
    const float* __restrict__ WhhF, const float* __restrict__ WhhB,
    const float* __restrict__ biasF, const float* __restrict__ biasB,
    const float* __restrict__ xproj,       // [S][4096]  (cols 0..2047 fwd, 2048.. bwd)
    unsigned int* __restrict__ Hx,         // [S][1024] f32-bits, poisoned 0xFFFFFFFF
    unsigned short* __restrict__ Hb)       // [S][1024] bf16 mirror
{
  const int S = S_LEN;
  const int dir = blockIdx.x & 1;
  const int chunk = blockIdx.x >> 1;       // 0..31
  const float* Whh = dir ? WhhB : WhhF;
  const float* bias = dir ? biasB : biasF;
  const int t = threadIdx.x;
  const int w = t >> 6, l = t & 63;
  const int g = l >> 4;            // gate 0..3 (i,f,g,o)
  const int jl = (l >> 3) & 1;     // element sub-index within wave
  const int o = l & 7;             // oct: h[o*64, o*64+64)
  const int elem = w * 2 + jl;     // 0..15
  const int r = g * 512 + chunk * 16 + elem;   // global gate row
  const int xoff = dir * 2048, hoff = dir * 512;

  const f32x4* wp = (const f32x4*)(Whh + (size_t)r * 512 + o * 64);   // 16 x dwordx4/step
  const float bv = bias[r];

  __shared__ float hsh[2][8 * 68];   // oct o at [o*68, o*68+64); parity double-buffer
  float c = 0.0f;
  const int slot = (t >> 6) * 68 + (t & 63);   // LDS slot for h element t

  float xp_cur = 0.0f;
  if (o == 0) {
    const int t0 = dir ? (S - 1) : 0;
    xp_cur = xproj[(size_t)t0 * 4096 + xoff + r] + bv;
  }

  for (int st = 0; st < S; st++) {
    const int tcur = dir ? (S - 1 - st) : st;
    const int pp = st & 1;
    const int tprev = dir ? (tcur + 1) : (tcur - 1);
    const unsigned int* src = Hx + (size_t)tprev * 1024 + hoff + t;

    // 1) first poll issued before anything else (oldest outstanding -> its check
    //    waits only vmcnt(<=16), weights keep flying)
    unsigned int v = 0;
    if (st > 0) v = __hip_atomic_load(src, __ATOMIC_RELAXED, __HIP_MEMORY_SCOPE_AGENT);

    // 2) weight stream: 16 x dwordx4, NO internal waitcnt -- they fly during the
    //    poison window. Validity before use is guaranteed by __syncthreads' vmcnt(0)
    //    drain. sched_barrier(0) pins them here (cannot be sunk past the barrier).
    f32x4 wv[16];
    #pragma unroll
    for (int i = 0; i < 16; i++)
      asm volatile("global_load_dwordx4 %0, %1, off" : "=v"(wv[i]) : "v"(wp + i));
    __builtin_amdgcn_sched_barrier(0);

    // 3) next step's xproj prefetch
    float xp_nxt = 0.0f;
    if (o == 0 && st + 1 < S) {
      const int tn = dir ? (S - 2 - st) : (st + 1);
      xp_nxt = xproj[(size_t)tn * 4096 + xoff + r] + bv;
    }

    // 4) poison spin (capped)
    if (st == 0) {
      hsh[0][slot] = 0.0f;                     // h_{-1} = 0
    } else {
      int cap = 1 << 16;                       // terminates under any pathology
      while (v == 0xFFFFFFFFu && --cap > 0)
        v = __hip_atomic_load(src, __ATOMIC_RELAXED, __HIP_MEMORY_SCOPE_AGENT);
      hsh[pp][slot] = __uint_as_float(v);
    }
    __syncthreads();                           // drains vmcnt(0): wv valid, LDS visible

    // 5) dot: oct o of row r against h (weights already in VGPRs)
    float acc = 0.0f;
    const float* hb = &hsh[pp][o * 68];
    #pragma unroll
    for (int i = 0; i < 16; i++) {
      f32x4 h4 = *(const f32x4*)&hb[4 * i];
      f32x4 ww = wv[i];
      acc = fmaf(ww[0], h4[0], acc);
      acc = fmaf(ww[1], h4[1], acc);
      acc = fmaf(ww[2], h4[2], acc);
      acc = fmaf(ww[3], h4[3], acc);
    }
    acc += __shfl_xor(acc, 1);
    acc += __shfl_xor(acc, 2);
    acc += __shfl_xor(acc, 4);
    acc += xp_cur;                             // xp_cur==0 in o!=0 lanes

    // 6) parallel gate nonlinearity in collector lanes (o==0), gather f,g,o
    const float av = (g == 2) ? tanhf_(acc) : sigm(acc);
    const float f_ = __shfl(av, (l & 8) + 16);
    const float g_ = __shfl(av, (l & 8) + 32);
    const float o_ = __shfl(av, (l & 8) + 48);

    if ((l & 55) == 0) {                       // lanes 0,8: own elem = w*2+jl
      c = f_ * c + av * g_;
      const float h = o_ * tanhf_(c);
      const size_t ofs = (size_t)tcur * 1024 + hoff + chunk * 16 + elem;
      __hip_atomic_store(Hx + ofs, __float_as_uint(h),
                         __ATOMIC_RELAXED, __HIP_MEMORY_SCOPE_AGENT);
      Hb[ofs] = f2bf(h);
    }
    xp_cur = xp_nxt;
    // one barrier/step: hsh parity-dbuf; next write to hsh[pp] is 2 barriers away
  }
}

// ---------------- launcher ----------------
extern "C" void kernel_launch(void* const* d_in, const int* in_sizes, int n_in,
                              void* d_out, int out_size, void* d_ws, size_t ws_size,
                              hipStream_t stream) {
  (void)in_sizes; (void)n_in; (void)out_size; (void)ws_size;
  const int*   input   = (const int*)d_in[0];
  const float* embed_w = (const float*)d_in[1];
  const float* Wih0f   = (const float*)d_in[2];
  const float* Whh0f   = (const float*)d_in[3];
  const float* b0f     = (const float*)d_in[4];
  const float* Wih0b   = (const float*)d_in[5];
  const float* Whh0b   = (const float*)d_in[6];
  const float* b0b     = (const float*)d_in[7];
  const float* Wih1f   = (const float*)d_in[8];
  const float* Whh1f   = (const float*)d_in[9];
  const float* b1f     = (const float*)d_in[10];
  const float* Wih1b   = (const float*)d_in[11];
  const float* Whh1b   = (const float*)d_in[12];
  const float* b1b     = (const float*)d_in[13];
  const float* Wlin    = (const float*)d_in[14];
  const float* blin    = (const float*)d_in[15];

  char* ws = (char*)d_ws;
  unsigned short* x0b   = (unsigned short*)(ws);                        // 4 MiB
  unsigned short* Wih0  = (unsigned short*)(ws + ((size_t)4  << 20));   // 4 MiB (stacked f;b)
  unsigned short* Wih1  = (unsigned short*)(ws + ((size_t)8  << 20));   // 8 MiB
  unsigned short* H0b   = (unsigned short*)(ws + ((size_t)16 << 20));   // 8 MiB
  unsigned short* H1b   = (unsigned short*)(ws + ((size_t)24 << 20));   // 8 MiB

  // big scratch lives in d_out (dead before head GEMM overwrites all of it)
  float* dout  = (float*)d_out;
  float* xproj = dout;                                             // 16Mi floats = 64 MiB
  unsigned int* H0 = (unsigned int*)(dout + ((size_t)16 << 20));   // 4Mi u32
  unsigned int* H1 = (unsigned int*)(dout + ((size_t)20 << 20));   // 4Mi u32

  // poison h-exchange buffers (data-as-flag: 0xFFFFFFFF unreachable since |h|<1)
  hipMemsetAsync(H0, 0xFF, (size_t)8 * 1024 * 1024 * 4, stream);   // H0+H1, 32 MiB

  embed_kernel<<<4096, 128, 0, stream>>>(input, embed_w, x0b);

  f32_to_bf16_kernel<<<1024, 256, 0, stream>>>(Wih0f, Wih0);
  f32_to_bf16_kernel<<<1024, 256, 0, stream>>>(Wih0b, Wih0 + (size_t)2048 * 512);
  f32_to_bf16_kernel<<<2048, 256, 0, stream>>>(Wih1f, Wih1);
  f32_to_bf16_kernel<<<2048, 256, 0, stream>>>(Wih1b, Wih1 + (size_t)2048 * 1024);

  // layer 0
  gemm_bt<false><<<32 * 32, 256, 0, stream>>>(x0b, Wih0, nullptr, xproj, 4096, 4096, 512);
  lstm_layer<<<64, 512, 0, stream>>>(Whh0f, Whh0b, b0f, b0b, xproj, H0, H0b);

  // layer 1
  gemm_bt<false><<<32 * 32, 256, 0, stream>>>(H0b, Wih1, nullptr, xproj, 4096, 4096, 1024);
  lstm_layer<<<64, 512, 0, stream>>>(Whh1f, Whh1b, b1f, b1b, xproj, H1, H1b);

  // output head: d_out = H1concat @ Wlin^T + blin
  gemm_bt<true><<<32 * 250, 256, 0, stream>>>(H1b, Wlin, blin, dout, 4096, 32000, 1024);
}

// Round 13
// 11826.901 us; speedup vs baseline: 3.6891x; 3.6891x over previous
//
#include <hip/hip_runtime.h>
#include <hip/hip_bf16.h>
#include <stdint.h>

#define S_LEN 4096

typedef __attribute__((ext_vector_type(8))) short short8;   // 8 bf16 in 4 VGPRs (MFMA frag)
typedef __attribute__((ext_vector_type(4))) float f32x4;

__device__ inline unsigned short f2bf(float f) {
  unsigned int x = __float_as_uint(f);
  x += 0x7fffu + ((x >> 16) & 1u);           // RNE; inputs finite
  return (unsigned short)(x >> 16);
}

__device__ inline float sigm(float x) { return 1.0f / (1.0f + __expf(-x)); }
__device__ inline float tanhf_(float x) {
  float e = __expf(-2.0f * fabsf(x));        // e in (0,1]: no overflow
  float t = (1.0f - e) / (1.0f + e);
  return copysignf(t, x);
}

__device__ inline void gload_lds16(const void* g, void* l) {
  __builtin_amdgcn_global_load_lds(
      (const __attribute__((address_space(1))) unsigned int*)g,
      (__attribute__((address_space(3))) unsigned int*)l, 16, 0, 0);
}

// ---------------- embedding gather: x0b[row][0:512) = bf16(E[idx[row]]) ----------------
__global__ void embed_kernel(const int* __restrict__ idx, const float* __restrict__ E,
                             unsigned short* __restrict__ x0b) {
  const int row = blockIdx.x;      // 4096
  const int t = threadIdx.x;       // 128
  const int id = idx[row];
  f32x4 v = ((const f32x4*)(E + (size_t)id * 512))[t];
  ushort4 u;
  u.x = f2bf(v[0]); u.y = f2bf(v[1]); u.z = f2bf(v[2]); u.w = f2bf(v[3]);
  ((ushort4*)(x0b + (size_t)row * 512))[t] = u;
}

// ---------------- f32 -> bf16 bulk convert ----------------
__global__ void f32_to_bf16_kernel(const float* __restrict__ src, unsigned short* __restrict__ dst) {
  const size_t i = (size_t)blockIdx.x * blockDim.x + threadIdx.x;
  f32x4 v = ((const f32x4*)src)[i];
  ushort4 u;
  u.x = f2bf(v[0]); u.y = f2bf(v[1]); u.z = f2bf(v[2]); u.w = f2bf(v[3]);
  ((ushort4*)dst)[i] = u;
}

// ---------------- bf16 MFMA GEMM, C[M][N] = A[M][K] @ B[N][K]^T (+bias) ----------------
template <bool BF32>
__global__ __launch_bounds__(256) void gemm_bt(
    const unsigned short* __restrict__ A,   // [M][K] bf16
    const void* __restrict__ Bsrc,          // [N][K] bf16 or f32
    const float* __restrict__ bias,         // [N] or nullptr
    float* __restrict__ C,                  // [M][N] f32
    int M, int N, int K)
{
  __shared__ unsigned short Al[128 * 32];
  __shared__ unsigned short Bl[128 * 32];
  const int tiles_n = N >> 7;
  const int tm = (blockIdx.x / tiles_n) << 7;
  const int tn = (blockIdx.x % tiles_n) << 7;
  const int t = threadIdx.x;
  const int w = t >> 6, l = t & 63;
  const int wr = w >> 1, wc = w & 1;

  f32x4 acc[4][4] = {};

  for (int k0 = 0; k0 < K; k0 += 32) {
    __syncthreads();
    {
      const int rb = w * 32;
      const unsigned short* ga = A + (size_t)(tm + rb + (l >> 2)) * K + k0 + (l & 3) * 8;
      gload_lds16(ga, &Al[rb * 32]);
      gload_lds16(ga + (size_t)16 * K, &Al[(rb + 16) * 32]);
    }
    if constexpr (!BF32) {
      const unsigned short* B = (const unsigned short*)Bsrc;
      const int rb = w * 32;
      const unsigned short* gb = B + (size_t)(tn + rb + (l >> 2)) * K + k0 + (l & 3) * 8;
      gload_lds16(gb, &Bl[rb * 32]);
      gload_lds16(gb + (size_t)16 * K, &Bl[(rb + 16) * 32]);
    } else {
      const float* B = (const float*)Bsrc;
      const int row = t >> 1, half = t & 1;
      const f32x4* src = (const f32x4*)(B + (size_t)(tn + row) * K + k0 + half * 16);
      f32x4 v0 = src[0], v1 = src[1], v2 = src[2], v3 = src[3];
      short8 p0, p1;
      p0[0] = f2bf(v0[0]); p0[1] = f2bf(v0[1]); p0[2] = f2bf(v0[2]); p0[3] = f2bf(v0[3]);
      p0[4] = f2bf(v1[0]); p0[5] = f2bf(v1[1]); p0[6] = f2bf(v1[2]); p0[7] = f2bf(v1[3]);
      p1[0] = f2bf(v2[0]); p1[1] = f2bf(v2[1]); p1[2] = f2bf(v2[2]); p1[3] = f2bf(v2[3]);
      p1[4] = f2bf(v3[0]); p1[5] = f2bf(v3[1]); p1[6] = f2bf(v3[2]); p1[7] = f2bf(v3[3]);
      *(short8*)&Bl[row * 32 + half * 16] = p0;
      *(short8*)&Bl[row * 32 + half * 16 + 8] = p1;
    }
    __syncthreads();

    const int lrow = l & 15;
    const int lkb = (l >> 4) * 8;
    short8 af[4], bfr[4];
    #pragma unroll
    for (int fm = 0; fm < 4; fm++)
      af[fm] = *(const short8*)&Al[(wr * 64 + fm * 16 + lrow) * 32 + lkb];
    #pragma unroll
    for (int fn = 0; fn < 4; fn++)
      bfr[fn] = *(const short8*)&Bl[(wc * 64 + fn * 16 + lrow) * 32 + lkb];
    #pragma unroll
    for (int fm = 0; fm < 4; fm++)
      #pragma unroll
      for (int fn = 0; fn < 4; fn++)
        acc[fm][fn] = __builtin_amdgcn_mfma_f32_16x16x32_bf16(af[fm], bfr[fn], acc[fm][fn], 0, 0, 0);
  }

  const int r0 = tm + wr * 64;
  const int c0 = tn + wc * 64 + (l & 15);
  const int rbase = (l >> 4) * 4;
  #pragma unroll
  for (int fm = 0; fm < 4; fm++) {
    #pragma unroll
    for (int fn = 0; fn < 4; fn++) {
      const int col = c0 + fn * 16;
      const float bv = bias ? bias[col] : 0.0f;
      #pragma unroll
      for (int rg = 0; rg < 4; rg++) {
        const int rr = r0 + fm * 16 + rbase + rg;
        C[(size_t)rr * N + col] = acc[fm][fn][rg] + bv;
      }
    }
  }
}

// ---------------- bidirectional LSTM layer (r7-proven best: 1.37us/step) ---------------
// grid = 64: dir = bid&1, chunk = bid>>1 (32 chunks of 16 h-elements each). 1 WG/CU.
// Lane map (wave w, lane l): gate g=l>>4, elem-sub jl=(l>>3)&1, oct o=l&7.
// Row r = g*512 + chunk*16 + (w*2+jl); oct o covers h[o*64, o*64+64).
// Weight stream: 16 x dwordx4/thread/step from L2 (the allocator provably won't keep
// 64 f32/thread resident: r5/r7 pins failed; LDS residency slower, r8; bf16 width and
// packed exchange null, r9; fewer/wider WG shapes thrash L2, r10/r11; manual overlap
// via no-wait asm catastrophic, r12 -- vmcnt retires in issue order, so any re-poll
// after the stream forces vmcnt(0) drain per spin iteration).
// Exchange: Hx dwords on 0xFFFFFFFF-poisoned buffer, relaxed AGENT atomics (|h|<1 so
// poison unreachable); each consumer tight-spins on its own word (capped -> always
// terminates). One barrier/step; hsh parity-double-buffered; parallel gate
// nonlinearities across collector lanes; xproj prefetched one step ahead.
// Step = producer compute (~0.3us) + MALL visibility (~0.4) + catch (~0.4) + barrier/
// LDS (~0.3) = 1.37us measured; 8192 serial steps = the lstm time. Latency-bound.
__global__ __launch_bounds__(512, 1) void lstm_layer(
    const float* __restrict__ WhhF, const float* __restrict__ WhhB,
    const float* __restrict__ biasF, const float* __restrict__ biasB,
    const float* __restrict__ xproj,       // [S][4096]  (cols 0..2047 fwd, 2048.. bwd)
    unsigned int* __restrict__ Hx,         // [S][1024] f32-bits, poisoned 0xFFFFFFFF
    unsigned short* __restrict__ Hb)       // [S][1024] bf16 mirror
{
  const int S = S_LEN;
  const int dir = blockIdx.x & 1;
  const int chunk = blockIdx.x >> 1;       // 0..31
  const float* Whh = dir ? WhhB : WhhF;
  const float* bias = dir ? biasB : biasF;
  const int t = threadIdx.x;
  const int w = t >> 6, l = t & 63;
  const int g = l >> 4;            // gate 0..3 (i,f,g,o)
  const int jl = (l >> 3) & 1;     // element sub-index within wave
  const int o = l & 7;             // oct: h[o*64, o*64+64)
  const int elem = w * 2 + jl;     // 0..15
  const int r = g * 512 + chunk * 16 + elem;   // global gate row
  const int xoff = dir * 2048, hoff = dir * 512;

  // 64 weight floats, loaded once through opaque volatile asm (kept: harmless, and
  // documents the failed-pin history; the allocator spills+restreams them from L2)
  f32x4 wv[16];
  {
    const f32x4* wp = (const f32x4*)(Whh + (size_t)r * 512 + o * 64);
    #pragma unroll
    for (int i = 0; i < 16; i++) {
      asm volatile("global_load_dwordx4 %0, %1, off\n\ts_waitcnt vmcnt(0)"
                   : "=v"(wv[i]) : "v"(wp + i) : "memory");
    }
  }
  const float bv = bias[r];

  __shared__ float hsh[2][8 * 68];   // oct o at [o*68, o*68+64); double-buffered by parity
  float c = 0.0f;
  const int slot = (t >> 6) * 68 + (t & 63);   // LDS slot for h element t

  float xp_cur = 0.0f;
  if (o == 0) {
    const int t0 = dir ? (S - 1) : 0;
    xp_cur = xproj[(size_t)t0 * 4096 + xoff + r] + bv;
  }

  for (int st = 0; st < S; st++) {
    const int tcur = dir ? (S - 1 - st) : st;
    const int pp = st & 1;

    // prefetch next step's xproj (hides latency under this whole step)
    float xp_nxt = 0.0f;
    if (o == 0 && st + 1 < S) {
      const int tn = dir ? (S - 2 - st) : (st + 1);
      xp_nxt = xproj[(size_t)tn * 4096 + xoff + r] + bv;
    }

    if (st == 0) {
      hsh[0][slot] = 0.0f;                     // h_{-1} = 0
    } else {
      const int tprev = dir ? (tcur + 1) : (tcur - 1);
      const unsigned int* src = Hx + (size_t)tprev * 1024 + hoff + t;
      unsigned int v;
      int cap = 1 << 16;                       // terminates under any pathology
      do {
        v = __hip_atomic_load(src, __ATOMIC_RELAXED, __HIP_MEMORY_SCOPE_AGENT);
      } while (v == 0xFFFFFFFFu && --cap > 0);
      hsh[pp][slot] = __uint_as_float(v);
    }
    __syncthreads();

    // dot: oct o of row r against h
    float acc = 0.0f;
    const float* hb = &hsh[pp][o * 68];
    #pragma unroll
    for (int i = 0; i < 16; i++) {
      f32x4 h4 = *(const f32x4*)&hb[4 * i];
      acc = fmaf(wv[i][0], h4[0], acc);
      acc = fmaf(wv[i][1], h4[1], acc);
      acc = fmaf(wv[i][2], h4[2], acc);
      acc = fmaf(wv[i][3], h4[3], acc);
    }
    acc += __shfl_xor(acc, 1);
    acc += __shfl_xor(acc, 2);
    acc += __shfl_xor(acc, 4);
    acc += xp_cur;                             // xp_cur==0 in o!=0 lanes

    // parallel gate nonlinearity in all collector lanes (o==0), then gather
    const float av = (g == 2) ? tanhf_(acc) : sigm(acc);
    const float f_ = __shfl(av, (l & 8) + 16);
    const float g_ = __shfl(av, (l & 8) + 32);
    const float o_ = __shfl(av, (l & 8) + 48);

    if ((l & 55) == 0) {                       // lanes 0,8: own elem = w*2+jl
      c = f_ * c + av * g_;
      const float h = o_ * tanhf_(c);
      const size_t ofs = (size_t)tcur * 1024 + hoff + chunk * 16 + elem;
      __hip_atomic_store(Hx + ofs, __float_as_uint(h),
                         __ATOMIC_RELAXED, __HIP_MEMORY_SCOPE_AGENT);
      Hb[ofs] = f2bf(h);
    }
    xp_cur = xp_nxt;
    // no second barrier: hsh double-buffered; next write to hsh[pp] is 2 barriers away
  }
}

// ---------------- launcher ----------------
extern "C" void kernel_launch(void* const* d_in, const int* in_sizes, int n_in,
                              void* d_out, int out_size, void* d_ws, size_t ws_size,
                              hipStream_t stream) {
  (void)in_sizes; (void)n_in; (void)out_size; (void)ws_size;
  const int*   input   = (const int*)d_in[0];
  const float* embed_w = (const float*)d_in[1];
  const float* Wih0f   = (const float*)d_in[2];
  const float* Whh0f   = (const float*)d_in[3];
  const float* b0f     = (const float*)d_in[4];
  const float* Wih0b   = (const float*)d_in[5];
  const float* Whh0b   = (const float*)d_in[6];
  const float* b0b     = (const float*)d_in[7];
  const float* Wih1f   = (const float*)d_in[8];
  const float* Whh1f   = (const float*)d_in[9];
  const float* b1f     = (const float*)d_in[10];
  const float* Wih1b   = (const float*)d_in[11];
  const float* Whh1b   = (const float*)d_in[12];
  const float* b1b     = (const float*)d_in[13];
  const float* Wlin    = (const float*)d_in[14];
  const float* blin    = (const float*)d_in[15];

  char* ws = (char*)d_ws;
  unsigned short* x0b   = (unsigned short*)(ws);                        // 4 MiB
  unsigned short* Wih0  = (unsigned short*)(ws + ((size_t)4  << 20));   // 4 MiB (stacked f;b)
  unsigned short* Wih1  = (unsigned short*)(ws + ((size_t)8  << 20));   // 8 MiB
  unsigned short* H0b   = (unsigned short*)(ws + ((size_t)16 << 20));   // 8 MiB
  unsigned short* H1b   = (unsigned short*)(ws + ((size_t)24 << 20));   // 8 MiB

  // big scratch lives in d_out (dead before head GEMM overwrites all of it)
  float* dout  = (float*)d_out;
  float* xproj = dout;                                             // 16Mi floats = 64 MiB
  unsigned int* H0 = (unsigned int*)(dout + ((size_t)16 << 20));   // 4Mi u32
  unsigned int* H1 = (unsigned int*)(dout + ((size_t)20 << 20));   // 4Mi u32

  // poison h-exchange buffers (data-as-flag: 0xFFFFFFFF unreachable since |h|<1)
  hipMemsetAsync(H0, 0xFF, (size_t)8 * 1024 * 1024 * 4, stream);   // H0+H1, 32 MiB

  embed_kernel<<<4096, 128, 0, stream>>>(input, embed_w, x0b);

  f32_to_bf16_kernel<<<1024, 256, 0, stream>>>(Wih0f, Wih0);
  f32_to_bf16_kernel<<<1024, 256, 0, stream>>>(Wih0b, Wih0 + (size_t)2048 * 512);
  f32_to_bf16_kernel<<<2048, 256, 0, stream>>>(Wih1f, Wih1);
  f32_to_bf16_kernel<<<2048, 256, 0, stream>>>(Wih1b, Wih1 + (size_t)2048 * 1024);

  // layer 0
  gemm_bt<false><<<32 * 32, 256, 0, stream>>>(x0b, Wih0, nullptr, xproj, 4096, 4096, 512);
  lstm_layer<<<64, 512, 0, stream>>>(Whh0f, Whh0b, b0f, b0b, xproj, H0, H0b);

  // layer 1
  gemm_bt<false><<<32 * 32, 256, 0, stream>>>(H0b, Wih1, nullptr, xproj, 4096, 4096, 1024);
  lstm_layer<<<64, 512, 0, stream>>>(Whh1f, Whh1b, b1f, b1b, xproj, H1, H1b);

  // output head: d_out = H1concat @ Wlin^T + blin
  gemm_bt<true><<<32 * 250, 256, 0, stream>>>(H1b, Wlin, blin, dout, 4096, 32000, 1024);
}